// Round 2
// baseline (260.320 us; speedup 1.0000x reference)
//
#include <hip/hip_runtime.h>
#include <hip/hip_bf16.h>

// Multi-LoRA column-parallel linear (shrink): y[row, o] = sum_i x[row, i] * W[ids[b], o, i]
//   x: [B=4, S=2048, D_IN=4096] f32   W: [32, 16, 4096] f32   ids: [4] i32
//   y: [8192, 16] f32
//
// Memory-bound: ~137 MB total traffic -> ~22 us roofline @ 6.3 TB/s achievable.
//
// Layout: one block = 512 threads = 8 waves = one row-group of RPG=8 rows.
//   wave w owns k-slice [w*512, (w+1)*512) (KSPLIT=8).
//   lane = (o, q): o = lane>>2 (16 outputs), q = lane&3 (4 k-sublanes).
//   Per iteration each lane loads one W float4 (16 distinct 64B lines/wave, L2-hot)
//   and 8 x float4 (addresses identical across the 16 o-groups -> TA merges to
//   ONE 64B line per row per iter, so x HBM traffic stays exactly 1x).
// Epilogue: shfl_xor over q, LDS reduce over the 8 k-splits, one coalesced
// 512B store per block. No atomics, no output pre-zeroing.

#define D_IN   4096
#define D_OUT  16
#define NROWS  8192          // B*S
#define RPG    8             // rows per block
#define KSPLIT 8             // waves per block, k-range 512 per wave
#define KRANGE (D_IN / KSPLIT)

__global__ __launch_bounds__(512, 8)
void multilora_shrink_kernel(const float* __restrict__ x,
                             const int*   __restrict__ ids,
                             const float* __restrict__ W,
                             float*       __restrict__ y) {
    const int lane = threadIdx.x & 63;
    const int koct = threadIdx.x >> 6;     // 0..7: which k-slice this wave owns
    const int row0 = blockIdx.x * RPG;     // 8 consecutive rows, same b (8 | 2048)
    const int b    = row0 >> 11;           // row0 / 2048
    const int a    = __builtin_amdgcn_readfirstlane(ids[b]);

    const float* __restrict__ Wa    = W + (size_t)a * (D_OUT * D_IN);
    const float* __restrict__ xbase = x + (size_t)row0 * D_IN;

    const int o = lane >> 2;   // 0..15 output index
    const int q = lane & 3;    // 0..3 k-sublane

    float acc[RPG];
#pragma unroll
    for (int r = 0; r < RPG; ++r) acc[r] = 0.0f;

    const int k0 = koct * KRANGE;
    const float* wrow = Wa + o * D_IN;

    for (int kc = k0; kc < k0 + KRANGE; kc += 16) {
        const int kk = kc + q * 4;
        const float4 wv = *(const float4*)(wrow + kk);
        float4 xv[RPG];
#pragma unroll
        for (int r = 0; r < RPG; ++r)
            xv[r] = *(const float4*)(xbase + r * D_IN + kk);
#pragma unroll
        for (int r = 0; r < RPG; ++r) {
            acc[r] = fmaf(xv[r].x, wv.x, acc[r]);
            acc[r] = fmaf(xv[r].y, wv.y, acc[r]);
            acc[r] = fmaf(xv[r].z, wv.z, acc[r]);
            acc[r] = fmaf(xv[r].w, wv.w, acc[r]);
        }
    }

    // reduce the 4 k-sublanes (q) within each o-group
#pragma unroll
    for (int r = 0; r < RPG; ++r) {
        acc[r] += __shfl_xor(acc[r], 1);
        acc[r] += __shfl_xor(acc[r], 2);
    }

    // cross-wave (k-split) reduction in LDS: part[koct][r][o]
    __shared__ float part[KSPLIT * RPG * D_OUT];   // 4 KB
    if (q == 0) {
#pragma unroll
        for (int r = 0; r < RPG; ++r)
            part[koct * (RPG * D_OUT) + r * D_OUT + o] = acc[r];
    }
    __syncthreads();

    const int tid = threadIdx.x;
    if (tid < RPG * D_OUT) {               // 128 threads: tid = r*16 + o
        float s = 0.0f;
#pragma unroll
        for (int ks = 0; ks < KSPLIT; ++ks)
            s += part[ks * (RPG * D_OUT) + tid];
        y[(size_t)row0 * D_OUT + tid] = s; // coalesced 512B per block
    }
}

extern "C" void kernel_launch(void* const* d_in, const int* in_sizes, int n_in,
                              void* d_out, int out_size, void* d_ws, size_t ws_size,
                              hipStream_t stream) {
    const float* x   = (const float*)d_in[0];
    const int*   ids = (const int*)  d_in[1];
    const float* W   = (const float*)d_in[2];
    float*       y   = (float*)d_out;

    multilora_shrink_kernel<<<NROWS / RPG, 512, 0, stream>>>(x, ids, W, y);
}

// Round 3
// 258.099 us; speedup vs baseline: 1.0086x; 1.0086x over previous
//
#include <hip/hip_runtime.h>
#include <hip/hip_bf16.h>

// Multi-LoRA column-parallel linear (shrink): y[row, o] = sum_i x[row, i] * W[ids[b], o, i]
//   x: [4, 2048, 4096] f32   W: [32, 16, 4096] f32   ids: [4] i32   y: [8192, 16] f32
//
// R2 post-mortem: 120 us, VALUBusy 20%, hbm 7% -> LATENCY-bound. VGPR_Count=24
// proved the compiler fused load+FMA loops (1 load in flight per wave).
// R3 fix: __launch_bounds__(512,2) lifts the VGPR cap (8-waves-min capped at 64),
// and an explicit A/B double-buffered phase loop makes >=9 loads outstanding a
// data dependence the scheduler must honor.
//
// Layout (unchanged): block = 8 waves = 8 rows x full k; wave w owns k-slice
// [w*512,(w+1)*512); lane=(o,q): o=lane>>2 (16 outputs), q=lane&3. x addresses
// duplicate 16x across o-groups -> TA merges to one 64B line per row per load,
// so x HBM traffic stays 1x. Epilogue: shfl over q, LDS reduce over 8 k-splits,
// one coalesced 512B store per block.

#define D_IN   4096
#define D_OUT  16
#define NROWS  8192
#define RPG    8             // rows per block
#define KSPLIT 8             // waves per block
#define KRANGE (D_IN / KSPLIT)

#define LOADV(XB, WB, KC) do {                                         \
    WB = *(const float4*)(wrow + (KC));                                \
    _Pragma("unroll")                                                  \
    for (int r = 0; r < RPG; ++r)                                      \
        XB[r] = *(const float4*)(xbase + r * D_IN + (KC));             \
} while (0)

#define FMAV(XB, WB) do {                                              \
    _Pragma("unroll")                                                  \
    for (int r = 0; r < RPG; ++r) {                                    \
        acc[r] = fmaf(XB[r].x, WB.x, acc[r]);                          \
        acc[r] = fmaf(XB[r].y, WB.y, acc[r]);                          \
        acc[r] = fmaf(XB[r].z, WB.z, acc[r]);                          \
        acc[r] = fmaf(XB[r].w, WB.w, acc[r]);                          \
    }                                                                  \
} while (0)

__global__ __launch_bounds__(512, 2)
void multilora_shrink_kernel(const float* __restrict__ x,
                             const int*   __restrict__ ids,
                             const float* __restrict__ W,
                             float*       __restrict__ y) {
    const int lane = threadIdx.x & 63;
    const int koct = threadIdx.x >> 6;     // 0..7: which 512-wide k-slice
    const int row0 = blockIdx.x * RPG;     // 8 consecutive rows, same b (8 | 2048)
    const int b    = row0 >> 11;
    const int a    = __builtin_amdgcn_readfirstlane(ids[b]);

    const float* __restrict__ Wa    = W + (size_t)a * (D_OUT * D_IN);
    const float* __restrict__ xbase = x + (size_t)row0 * D_IN;

    const int o = lane >> 2;   // 0..15 output index
    const int q = lane & 3;    // 0..3  k-sublane

    const float* wrow = Wa + o * D_IN;

    float acc[RPG];
#pragma unroll
    for (int r = 0; r < RPG; ++r) acc[r] = 0.0f;

    // -------- double-buffered k-loop: 32 load-phases of 16 floats each --------
    float4 xA[RPG], xB[RPG], wA, wB;
    int kc = koct * KRANGE + q * 4;

    LOADV(xA, wA, kc);                 // prologue: fill buffer A
#pragma unroll 1
    for (int i = 0; i < 15; ++i) {
        LOADV(xB, wB, kc + 16);        // prefetch B while A is in flight/consumed
        FMAV(xA, wA);
        LOADV(xA, wA, kc + 32);        // prefetch A while B consumed
        FMAV(xB, wB);
        kc += 32;
    }
    LOADV(xB, wB, kc + 16);            // last load (covers k...+496)
    FMAV(xA, wA);
    FMAV(xB, wB);

    // -------- reduce 4 k-sublanes (q) within each o-group --------
#pragma unroll
    for (int r = 0; r < RPG; ++r) {
        acc[r] += __shfl_xor(acc[r], 1);
        acc[r] += __shfl_xor(acc[r], 2);
    }

    // -------- cross-wave (k-split) reduction in LDS --------
    __shared__ float part[KSPLIT * RPG * D_OUT];   // 4 KB
    if (q == 0) {
#pragma unroll
        for (int r = 0; r < RPG; ++r)
            part[koct * (RPG * D_OUT) + r * D_OUT + o] = acc[r];
    }
    __syncthreads();

    const int tid = threadIdx.x;
    if (tid < RPG * D_OUT) {           // 128 threads: tid = r*16 + o
        float s = 0.0f;
#pragma unroll
        for (int ks = 0; ks < KSPLIT; ++ks)
            s += part[ks * (RPG * D_OUT) + tid];
        y[(size_t)row0 * D_OUT + tid] = s;
    }
}

extern "C" void kernel_launch(void* const* d_in, const int* in_sizes, int n_in,
                              void* d_out, int out_size, void* d_ws, size_t ws_size,
                              hipStream_t stream) {
    const float* x   = (const float*)d_in[0];
    const int*   ids = (const int*)  d_in[1];
    const float* W   = (const float*)d_in[2];
    float*       y   = (float*)d_out;

    multilora_shrink_kernel<<<NROWS / RPG, 512, 0, stream>>>(x, ids, W, y);
}

// Round 6
// 197.064 us; speedup vs baseline: 1.3210x; 1.3097x over previous
//
#include <hip/hip_runtime.h>
#include <hip/hip_bf16.h>

// Multi-LoRA shrink as MFMA GEMM: y[m, o] = sum_k x[m, k] * W[ids[b], o, k]
//   x: [8192, 4096] f32   W: [32, 16, 4096] f32   ids: [4] i32   y: [8192, 16] f32
//
// R2/R3 post-mortem: 120us / 117us IDENTICAL across 2x occupancy and 2.3x VGPR
// changes -> VMEM request-path wall, not latency. The lane=(o,q) layout
// duplicated every x line 16x across o-groups => ~16x request amplification.
// Fix: MFMA 16x16x32_bf16. A-frag lane reads 8 CONSECUTIVE distinct fp32 of its
// x row (dense 1KB/wave-load, no duplication); o-sharing happens in the matrix
// pipe. fp32 accuracy via split bf16: x=xh+xl, W=wh+wl,
// acc += xh*wh + xl*wh + xh*wl (residual ~2e-5 << passing absmax 0.0078).
// VALU audit (R5): cvt chain ~800 wave-inst/wave -> ~5-7us total, under the
// ~21us memory floor; kernel is memory-bound by design.
//
// Block = 512 thr = 8 waves = 8 k-splits (512 k each) of ONE 16-row tile.
// Epilogue: LDS combine of 8 partial C-frags, one contiguous 1KB store.
// Fragment pattern = verified m91/m92 gemm_bt (both operands: 8-consecutive-K
// at row l&15, k-half (l>>4)*8); C/D: col=l&15, row=(l>>4)*4+reg (m89/m91).

#define D_IN   4096
#define D_OUT  16
#define NROWS  8192
#define TM     16                 // rows per block (MFMA M)
#define KSPLIT 8                  // waves per block
#define KRANGE (D_IN / KSPLIT)    // 512
#define KSTEP  32                 // MFMA K
#define NSTEP  (KRANGE / KSTEP)   // 16

typedef float f32x4  __attribute__((ext_vector_type(4)));
typedef short short8 __attribute__((ext_vector_type(8)));   // 8 bf16 bits (4 VGPRs)

struct Buf8 { f32x4 lo, hi; };    // 8 consecutive fp32

#define LOAD8(B, P, OFF) do {                                   \
    (B).lo = *(const f32x4*)((P) + (OFF));                      \
    (B).hi = *(const f32x4*)((P) + (OFF) + 4);                  \
} while (0)

// split f into hi/lo bf16 halves (native __bf16 casts -> compiler emits v_cvt)
__device__ __forceinline__ void cvt_hilo(const Buf8& b, short8& h, short8& l) {
#pragma unroll
    for (int j = 0; j < 8; ++j) {
        float f  = (j < 4) ? b.lo[j] : b.hi[j - 4];
        __bf16 hb = (__bf16)f;                 // RNE
        float  rem = f - (float)hb;
        __bf16 lb = (__bf16)rem;
        h[j] = __builtin_bit_cast(short, hb);
        l[j] = __builtin_bit_cast(short, lb);
    }
}

#define STEP(XB, WB) do {                                                        \
    short8 xh, xl, wh, wl;                                                       \
    cvt_hilo(XB, xh, xl);                                                        \
    cvt_hilo(WB, wh, wl);                                                        \
    acc = __builtin_amdgcn_mfma_f32_16x16x32_bf16(xh, wh, acc, 0, 0, 0);         \
    acc = __builtin_amdgcn_mfma_f32_16x16x32_bf16(xl, wh, acc, 0, 0, 0);         \
    acc = __builtin_amdgcn_mfma_f32_16x16x32_bf16(xh, wl, acc, 0, 0, 0);         \
} while (0)

__global__ __launch_bounds__(512, 4)
void multilora_shrink_mfma(const float* __restrict__ x,
                           const int*   __restrict__ ids,
                           const float* __restrict__ W,
                           float*       __restrict__ y) {
    const int l    = threadIdx.x & 63;
    const int w    = threadIdx.x >> 6;        // 0..7: k-split
    const int row0 = blockIdx.x * TM;         // 16 rows, same b (16 | 2048)
    const int a    = ids[row0 >> 11];         // block-uniform -> scalar load

    const int fr = l & 15;                    // A: x-row / B: o column
    const int fk = (l >> 4) * 8;              // this lane's 8-elem k-offset

    const float* xp = x + (size_t)(row0 + fr) * D_IN + w * KRANGE + fk;
    const float* wp = W + (size_t)a * (D_OUT * D_IN) + (size_t)fr * D_IN + w * KRANGE + fk;

    f32x4 acc = {0.f, 0.f, 0.f, 0.f};

    Buf8 xA, wA, xB, wB;
    LOAD8(xA, xp, 0);
    LOAD8(wA, wp, 0);
#pragma unroll 1
    for (int i = 0; i < (NSTEP - 2) / 2; ++i) {      // 7 iters, steps 0..13
        LOAD8(xB, xp, (2 * i + 1) * KSTEP);
        LOAD8(wB, wp, (2 * i + 1) * KSTEP);
        STEP(xA, wA);
        LOAD8(xA, xp, (2 * i + 2) * KSTEP);
        LOAD8(wA, wp, (2 * i + 2) * KSTEP);
        STEP(xB, wB);
    }
    LOAD8(xB, xp, (NSTEP - 1) * KSTEP);
    LOAD8(wB, wp, (NSTEP - 1) * KSTEP);
    STEP(xA, wA);                                    // step 14
    STEP(xB, wB);                                    // step 15

    // ---- combine the 8 k-split partial C tiles in LDS ----
    // lane l, reg r holds y[row0 + (l>>4)*4 + r][o = l&15]; store col-major
    // (idx = o*16 + row) so each lane's 4 floats are one contiguous f32x4.
    __shared__ float part[KSPLIT * TM * D_OUT];      // 8 KB
    {
        const int base = w * (TM * D_OUT) + fr * TM + (l >> 4) * 4;
        *(f32x4*)&part[base] = acc;
    }
    __syncthreads();

    const int t = threadIdx.x;
    if (t < TM * D_OUT) {                            // t = row*16 + o
        const int row = t >> 4, o = t & 15;
        float s = 0.f;
#pragma unroll
        for (int ks = 0; ks < KSPLIT; ++ks)
            s += part[ks * (TM * D_OUT) + o * TM + row];
        y[(size_t)row0 * D_OUT + t] = s;             // contiguous 1KB per block
    }
}

extern "C" void kernel_launch(void* const* d_in, const int* in_sizes, int n_in,
                              void* d_out, int out_size, void* d_ws, size_t ws_size,
                              hipStream_t stream) {
    const float* x   = (const float*)d_in[0];
    const int*   ids = (const int*)  d_in[1];
    const float* W   = (const float*)d_in[2];
    float*       y   = (float*)d_out;

    multilora_shrink_mfma<<<NROWS / TM, 512, 0, stream>>>(x, ids, W, y);
}

// Round 7
// 194.861 us; speedup vs baseline: 1.3359x; 1.0113x over previous
//
#include <hip/hip_runtime.h>
#include <hip/hip_bf16.h>

// Multi-LoRA shrink as MFMA GEMM: y[m, o] = sum_k x[m, k] * W[ids[b], o, k]
//   x: [8192, 4096] f32   W: [32, 16, 4096] f32   ids: [4] i32   y: [8192, 16] f32
//
// Ladder: R2/R3 lane=(o,q) 120/117us (VMEM request wall, 16x same-line dup)
//         R6 MFMA 16x16x32 split-bf16 ~56us (request wall gone; now latency-
//            stalled: depth-1 prefetch = 200cyc gap vs 500-900cyc load latency,
//            ~600cyc stall x 16 steps/wave)
// R7: depth-4 rotating prefetch (A/B/C/D) -> prefetch distance 3 steps (~600cyc
//     of cvt+MFMA work) covers L3/L2 latency within-wave. All buffer indices
//     static (rule #20). VGPR ~105 < 128 cap.
//
// Block = 512 thr = 8 waves = 8 k-splits (512 k each) of ONE 16-row tile.
// Fragments (verified m89/m91): A/B lane reads 8 consecutive K at row l&15,
// k-half (l>>4)*8; C/D reg r -> y[(l>>4)*4+r][l&15]. fp32 via split bf16:
// acc += xh*wh + xl*wh + xh*wl (residual ~1e-4 << passing absmax 1.6e-2).

#define D_IN   4096
#define D_OUT  16
#define NROWS  8192
#define TM     16                 // rows per block (MFMA M)
#define KSPLIT 8                  // waves per block
#define KRANGE (D_IN / KSPLIT)    // 512
#define KSTEP  32                 // MFMA K
#define NSTEP  (KRANGE / KSTEP)   // 16

typedef float f32x4  __attribute__((ext_vector_type(4)));
typedef short short8 __attribute__((ext_vector_type(8)));   // 8 bf16 (4 VGPRs)

struct Buf8 { f32x4 lo, hi; };    // 8 consecutive fp32

// load x and W fragments for k-step S into named buffers XB/WB
#define LOADP(XB, WB, S) do {                                   \
    (XB).lo = *(const f32x4*)(xp + (S) * KSTEP);                \
    (XB).hi = *(const f32x4*)(xp + (S) * KSTEP + 4);            \
    (WB).lo = *(const f32x4*)(wp + (S) * KSTEP);                \
    (WB).hi = *(const f32x4*)(wp + (S) * KSTEP + 4);            \
} while (0)

__device__ __forceinline__ void cvt_hilo(const Buf8& b, short8& h, short8& l) {
#pragma unroll
    for (int j = 0; j < 8; ++j) {
        float f  = (j < 4) ? b.lo[j] : b.hi[j - 4];
        __bf16 hb = (__bf16)f;                 // RNE
        float  rem = f - (float)hb;
        __bf16 lb = (__bf16)rem;
        h[j] = __builtin_bit_cast(short, hb);
        l[j] = __builtin_bit_cast(short, lb);
    }
}

#define STEP(XB, WB) do {                                                        \
    short8 xh, xl, wh, wl;                                                       \
    cvt_hilo(XB, xh, xl);                                                        \
    cvt_hilo(WB, wh, wl);                                                        \
    acc = __builtin_amdgcn_mfma_f32_16x16x32_bf16(xh, wh, acc, 0, 0, 0);         \
    acc = __builtin_amdgcn_mfma_f32_16x16x32_bf16(xl, wh, acc, 0, 0, 0);         \
    acc = __builtin_amdgcn_mfma_f32_16x16x32_bf16(xh, wl, acc, 0, 0, 0);         \
} while (0)

__global__ __launch_bounds__(512, 4)
void multilora_shrink_mfma(const float* __restrict__ x,
                           const int*   __restrict__ ids,
                           const float* __restrict__ W,
                           float*       __restrict__ y) {
    const int l    = threadIdx.x & 63;
    const int w    = threadIdx.x >> 6;        // 0..7: k-split
    const int row0 = blockIdx.x * TM;         // 16 rows, same b (16 | 2048)
    const int a    = ids[row0 >> 11];         // block-uniform -> scalar load

    const int fr = l & 15;                    // A: x-row / B: o column
    const int fk = (l >> 4) * 8;              // this lane's 8-elem k-offset

    const float* xp = x + (size_t)(row0 + fr) * D_IN + w * KRANGE + fk;
    const float* wp = W + (size_t)a * (D_OUT * D_IN) + (size_t)fr * D_IN + w * KRANGE + fk;

    f32x4 acc = {0.f, 0.f, 0.f, 0.f};

    // ---- depth-4 rotating pipeline over NSTEP=16 k-steps ----
    Buf8 xA, wA, xB, wB, xC, wC, xD, wD;
    LOADP(xA, wA, 0);
    LOADP(xB, wB, 1);
    LOADP(xC, wC, 2);
    LOADP(xD, wD, 3);
#pragma unroll 1
    for (int i = 0; i < (NSTEP - 4) / 4; ++i) {      // i=0..2: consume 4i..4i+3
        STEP(xA, wA); LOADP(xA, wA, 4 * i + 4);
        STEP(xB, wB); LOADP(xB, wB, 4 * i + 5);
        STEP(xC, wC); LOADP(xC, wC, 4 * i + 6);
        STEP(xD, wD); LOADP(xD, wD, 4 * i + 7);
    }
    STEP(xA, wA);                                    // steps 12..15
    STEP(xB, wB);
    STEP(xC, wC);
    STEP(xD, wD);

    // ---- combine the 8 k-split partial C tiles in LDS ----
    // store col-major (idx = o*16 + row): each lane's 4 floats contiguous
    __shared__ float part[KSPLIT * TM * D_OUT];      // 8 KB
    {
        const int base = w * (TM * D_OUT) + fr * TM + (l >> 4) * 4;
        *(f32x4*)&part[base] = acc;
    }
    __syncthreads();

    const int t = threadIdx.x;
    if (t < TM * D_OUT) {                            // t = row*16 + o
        const int row = t >> 4, o = t & 15;
        float s = 0.f;
#pragma unroll
        for (int ks = 0; ks < KSPLIT; ++ks)
            s += part[ks * (TM * D_OUT) + o * TM + row];
        y[(size_t)row0 * D_OUT + t] = s;             // contiguous 1KB per block
    }
}

extern "C" void kernel_launch(void* const* d_in, const int* in_sizes, int n_in,
                              void* d_out, int out_size, void* d_ws, size_t ws_size,
                              hipStream_t stream) {
    const float* x   = (const float*)d_in[0];
    const int*   ids = (const int*)  d_in[1];
    const float* W   = (const float*)d_in[2];
    float*       y   = (float*)d_out;

    multilora_shrink_mfma<<<NROWS / TM, 512, 0, stream>>>(x, ids, W, y);
}